// Round 14
// baseline (56.590 us; speedup 1.0000x reference)
//
#include <hip/hip_runtime.h>

#define Lr 2048
#define Dr 1024
#define Nr 16
#define Gc 64           // chunks along L
#define LC (Lr/Gc)      // 32
#define DN (Dr*Nr)      // 16384
#define GDN (Gc*DN)

#define LOG2E 1.442695041f
#define LN2   0.69314718056f

typedef float f32x4 __attribute__((ext_vector_type(4)));

__device__ __forceinline__ float exp2_hw(float x){ return __builtin_amdgcn_exp2f(x); }
__device__ __forceinline__ float log2_hw(float x){ return __builtin_amdgcn_logf(x); }
__device__ __forceinline__ float exp_hw(float x) { return exp2_hw(x*LOG2E); }
__device__ __forceinline__ float softplus_fast(float x){
  float t = exp2_hw(-LOG2E*fabsf(x));
  return fmaxf(x, 0.f) + LN2*log2_hw(1.f + t);
}

// z[l] = dot(xs[l,:], WD) + bD  (separate tiny kernel; folding into phase
// kernels costs 16x redundant xs reads, +50us measured R9)
__global__ void k_rowdot(const float* __restrict__ xs, const float* __restrict__ WD,
                         const float* __restrict__ bD, float* __restrict__ z){
  int l = blockIdx.x;
  const float4* row = (const float4*)(xs + (size_t)l*Dr);
  const float4* w4  = (const float4*)WD;
  int i = threadIdx.x;           // Dr/4 == 256 == blockDim
  float4 a = row[i], b = w4[i];
  float s = fmaf(a.x,b.x, fmaf(a.y,b.y, fmaf(a.z,b.z, a.w*b.w)));
  #pragma unroll
  for (int off = 32; off > 0; off >>= 1) s += __shfl_down(s, off, 64);
  __shared__ float red[4];
  int wid = threadIdx.x >> 6, lane = threadIdx.x & 63;
  if (lane == 0) red[wid] = s;
  __syncthreads();
  if (threadIdx.x == 0) z[l] = red[0] + red[1] + red[2] + red[3] + bD[0];
}

// Phase 1: thread per (g, d, n-quad); 4 chains/thread; n4-fastest lane map
// (whole-line wave stores; d-fastest variant caused cross-XCD partial-line
// RMW, +7us, R12). Scan algebra: B' = Ab*(B+w) - w (2 ops vs 3).
__global__ __launch_bounds__(256) void k_phase1(
    const float* __restrict__ xs, const float* __restrict__ WB,
    const float* __restrict__ bB,
    const float* __restrict__ lnA, const float* __restrict__ dparam,
    const float* __restrict__ z,
    float* __restrict__ aggA, float* __restrict__ aggB){
  int t  = blockIdx.x*256 + threadIdx.x;
  int g  = t >> 12;             // Dr*4 = 4096 threads per chunk
  int r  = t & 4095;
  int d  = r >> 2;
  int n4 = r & 3;
  float4 la = *(const float4*)(lnA + d*Nr + n4*4);
  float4 wb = *(const float4*)(WB  + n4*4);
  float4 bb = *(const float4*)(bB  + n4*4);
  float lav[4] = {la.x,la.y,la.z,la.w};
  float wbv[4] = {wb.x,wb.y,wb.z,wb.w};
  float bbv[4] = {bb.x,bb.y,bb.z,bb.w};
  float ad2[4], p[4], q[4], Ap[4], Bc[4];
  #pragma unroll
  for (int j=0;j<4;j++){
    float a = -exp_hw(lav[j]);
    ad2[j] = a*LOG2E;
    float ia = 1.f/a;
    p[j]=wbv[j]*ia; q[j]=bbv[j]*ia; Ap[j]=1.f; Bc[j]=0.f;
  }
  float dp = dparam[d];
  int l0 = g*LC;
  #pragma unroll 2
  for (int i=0;i<LC;i++){
    int l = l0+i;
    float x  = xs[(size_t)l*Dr + d];
    float dl = softplus_fast(dp + z[l]);
    float x2 = x*x;
    #pragma unroll
    for (int j=0;j<4;j++){
      float Ab = exp2_hw(dl*ad2[j]);
      float w  = fmaf(x2, p[j], x*q[j]);
      Ap[j] *= Ab;
      Bc[j] = fmaf(Ab, Bc[j]+w, -w);
    }
  }
  *(float4*)(aggA + (size_t)g*DN + d*Nr + n4*4) = make_float4(Ap[0],Ap[1],Ap[2],Ap[3]);
  *(float4*)(aggB + (size_t)g*DN + d*Nr + n4*4) = make_float4(Bc[0],Bc[1],Bc[2],Bc[3]);
}

// Phase 2 (R5-proven): per-chain serial scan over 64 chunks; unroll 8.
__global__ __launch_bounds__(64) void k_carry(
    const float* __restrict__ aggA, const float* __restrict__ aggB,
    float* __restrict__ carry){
  const int t = blockIdx.x*64 + threadIdx.x;   // chain id = d*Nr+n
  float h = 0.f;
  #pragma unroll 8
  for (int g=0; g<Gc; g++){
    carry[(size_t)g*DN + t] = h;
    h = fmaf(aggA[(size_t)g*DN + t], h, aggB[(size_t)g*DN + t]);
  }
}

// Phase 3: n4-fastest lane map, PLAIN f32x4 stores (nt regressed +5us, R13);
// unroll 4 for load/store ILP; h' = Ab*(h+w) - w algebra.
__global__ __launch_bounds__(256) void k_phase3(
    const float* __restrict__ xs, const float* __restrict__ WB,
    const float* __restrict__ bB, const float* __restrict__ WC,
    const float* __restrict__ bC,
    const float* __restrict__ lnA, const float* __restrict__ dparam,
    const float* __restrict__ z, const float* __restrict__ carry,
    float* __restrict__ ys, float* __restrict__ hs){
  int t  = blockIdx.x*256 + threadIdx.x;
  int g  = t >> 12;
  int r  = t & 4095;
  int d  = r >> 2;
  int n4 = r & 3;
  float4 la = *(const float4*)(lnA + d*Nr + n4*4);
  float4 wb = *(const float4*)(WB  + n4*4);
  float4 bb = *(const float4*)(bB  + n4*4);
  float4 wcv= *(const float4*)(WC  + n4*4);
  float4 bcv= *(const float4*)(bC  + n4*4);
  float4 h0 = *(const float4*)(carry + (size_t)g*DN + d*Nr + n4*4);
  float lav[4] = {la.x,la.y,la.z,la.w};
  float wbv[4] = {wb.x,wb.y,wb.z,wb.w};
  float bbv[4] = {bb.x,bb.y,bb.z,bb.w};
  float wc[4]  = {wcv.x,wcv.y,wcv.z,wcv.w};
  float bc[4]  = {bcv.x,bcv.y,bcv.z,bcv.w};
  float h[4]   = {h0.x,h0.y,h0.z,h0.w};
  float ad2[4], p[4], q[4];
  #pragma unroll
  for (int j=0;j<4;j++){
    float a = -exp_hw(lav[j]);
    ad2[j] = a*LOG2E;
    float ia = 1.f/a;
    p[j]=wbv[j]*ia; q[j]=bbv[j]*ia;
  }
  float dp = dparam[d];
  int l0 = g*LC;
  #pragma unroll 4
  for (int i=0;i<LC;i++){
    int l = l0+i;
    float x  = xs[(size_t)l*Dr + d];
    float dl = softplus_fast(dp + z[l]);
    float x2 = x*x;
    float y = 0.f;
    #pragma unroll
    for (int j=0;j<4;j++){
      float Ab = exp2_hw(dl*ad2[j]);
      float w  = fmaf(x2, p[j], x*q[j]);
      h[j] = fmaf(Ab, h[j]+w, -w);
      y = fmaf(h[j], fmaf(x, wc[j], bc[j]), y);
    }
    *(f32x4*)(hs + (size_t)l*DN + d*Nr + n4*4) = (f32x4){h[0],h[1],h[2],h[3]};
    // reduce y over the 4 n-lanes sharing this d (lanes 4k..4k+3)
    y += __shfl_xor(y, 1, 64);
    y += __shfl_xor(y, 2, 64);
    if (n4 == 0) ys[(size_t)l*Dr + d] = y;
  }
}

extern "C" void kernel_launch(void* const* d_in, const int* in_sizes, int n_in,
                              void* d_out, int out_size, void* d_ws, size_t ws_size,
                              hipStream_t stream) {
  const float* xs     = (const float*)d_in[0];
  const float* WB     = (const float*)d_in[1];
  const float* bB     = (const float*)d_in[2];
  const float* WC     = (const float*)d_in[3];
  const float* bC     = (const float*)d_in[4];
  const float* WD     = (const float*)d_in[5];
  const float* bD     = (const float*)d_in[6];
  const float* lnA    = (const float*)d_in[7];
  const float* dparam = (const float*)d_in[8];

  float* ys = (float*)d_out;
  float* hs = ys + (size_t)Lr*Dr;

  float* z     = (float*)d_ws;          // Lr
  float* aggA  = z + Lr;                // GDN (4 MB)
  float* aggB  = aggA + GDN;            // GDN
  float* carry = aggB + GDN;            // GDN  (total ~12.6 MB)

  k_rowdot<<<Lr, 256, 0, stream>>>(xs, WD, bD, z);
  k_phase1<<<(Gc*Dr*4)/256, 256, 0, stream>>>(xs, WB, bB, lnA, dparam, z, aggA, aggB);
  k_carry<<<DN/64, 64, 0, stream>>>(aggA, aggB, carry);
  k_phase3<<<(Gc*Dr*4)/256, 256, 0, stream>>>(xs, WB, bB, WC, bC, lnA, dparam, z, carry, ys, hs);
}

// Round 15
// 56.158 us; speedup vs baseline: 1.0077x; 1.0077x over previous
//
#include <hip/hip_runtime.h>

#define Lr 2048
#define Dr 1024
#define Nr 16
#define Gc 64           // chunks along L
#define LC (Lr/Gc)      // 32
#define DN (Dr*Nr)      // 16384
#define GDN (Gc*DN)

#define LOG2E 1.442695041f
#define LN2   0.69314718056f

typedef float f32x4 __attribute__((ext_vector_type(4)));

__device__ __forceinline__ float exp2_hw(float x){ return __builtin_amdgcn_exp2f(x); }
__device__ __forceinline__ float log2_hw(float x){ return __builtin_amdgcn_logf(x); }
__device__ __forceinline__ float exp_hw(float x) { return exp2_hw(x*LOG2E); }
__device__ __forceinline__ float softplus_fast(float x){
  float t = exp2_hw(-LOG2E*fabsf(x));
  return fmaxf(x, 0.f) + LN2*log2_hw(1.f + t);
}

// z[l] = dot(xs[l,:], WD) + bD  (separate tiny kernel; folding into phase
// kernels costs 16x redundant xs reads, +50us measured R9)
__global__ void k_rowdot(const float* __restrict__ xs, const float* __restrict__ WD,
                         const float* __restrict__ bD, float* __restrict__ z){
  int l = blockIdx.x;
  const float4* row = (const float4*)(xs + (size_t)l*Dr);
  const float4* w4  = (const float4*)WD;
  int i = threadIdx.x;           // Dr/4 == 256 == blockDim
  float4 a = row[i], b = w4[i];
  float s = fmaf(a.x,b.x, fmaf(a.y,b.y, fmaf(a.z,b.z, a.w*b.w)));
  #pragma unroll
  for (int off = 32; off > 0; off >>= 1) s += __shfl_down(s, off, 64);
  __shared__ float red[4];
  int wid = threadIdx.x >> 6, lane = threadIdx.x & 63;
  if (lane == 0) red[wid] = s;
  __syncthreads();
  if (threadIdx.x == 0) z[l] = red[0] + red[1] + red[2] + red[3] + bD[0];
}

// Phase 1 (R5-proven): thread per (g, d, n-quad); 4 chains/thread; n4-fastest
// lane map so each agg float4 store instr is wave-contiguous 1KB (whole lines
// from one wave — d-fastest variant caused cross-XCD partial-line RMW, R12).
__global__ __launch_bounds__(256) void k_phase1(
    const float* __restrict__ xs, const float* __restrict__ WB,
    const float* __restrict__ bB,
    const float* __restrict__ lnA, const float* __restrict__ dparam,
    const float* __restrict__ z,
    float* __restrict__ aggA, float* __restrict__ aggB){
  int t  = blockIdx.x*256 + threadIdx.x;
  int g  = t >> 12;             // Dr*4 = 4096 threads per chunk
  int r  = t & 4095;
  int d  = r >> 2;
  int n4 = r & 3;
  float4 la = *(const float4*)(lnA + d*Nr + n4*4);
  float4 wb = *(const float4*)(WB  + n4*4);
  float4 bb = *(const float4*)(bB  + n4*4);
  float lav[4] = {la.x,la.y,la.z,la.w};
  float wbv[4] = {wb.x,wb.y,wb.z,wb.w};
  float bbv[4] = {bb.x,bb.y,bb.z,bb.w};
  float ad2[4], p[4], q[4], Ap[4], Bc[4];
  #pragma unroll
  for (int j=0;j<4;j++){
    float a = -exp_hw(lav[j]);
    ad2[j] = a*LOG2E;
    float ia = 1.f/a;
    p[j]=wbv[j]*ia; q[j]=bbv[j]*ia; Ap[j]=1.f; Bc[j]=0.f;
  }
  float dp = dparam[d];
  int l0 = g*LC;
  #pragma unroll 2
  for (int i=0;i<LC;i++){
    int l = l0+i;
    float x  = xs[(size_t)l*Dr + d];
    float dl = softplus_fast(dp + z[l]);
    float x2 = x*x;
    #pragma unroll
    for (int j=0;j<4;j++){
      float Ab = exp2_hw(dl*ad2[j]);
      float Bx = (Ab-1.f)*fmaf(x2, p[j], x*q[j]);
      Ap[j] *= Ab;
      Bc[j] = fmaf(Ab, Bc[j], Bx);
    }
  }
  *(float4*)(aggA + (size_t)g*DN + d*Nr + n4*4) = make_float4(Ap[0],Ap[1],Ap[2],Ap[3]);
  *(float4*)(aggB + (size_t)g*DN + d*Nr + n4*4) = make_float4(Bc[0],Bc[1],Bc[2],Bc[3]);
}

// Phase 2 (R5-proven): per-chain serial scan over 64 chunks; unroll 8.
__global__ __launch_bounds__(64) void k_carry(
    const float* __restrict__ aggA, const float* __restrict__ aggB,
    float* __restrict__ carry){
  const int t = blockIdx.x*64 + threadIdx.x;   // chain id = d*Nr+n
  float h = 0.f;
  #pragma unroll 8
  for (int g=0; g<Gc; g++){
    carry[(size_t)g*DN + t] = h;
    h = fmaf(aggA[(size_t)g*DN + t], h, aggB[(size_t)g*DN + t]);
  }
}

// Phase 3 (ledger best, R13): n4-fastest lane map; PLAIN f32x4 stores —
// nontemporal measured +5us (R13 A/B): nt bypasses L2 write-combining and
// loses to the L2 write-back path even for full-line streaming writes.
__global__ __launch_bounds__(256) void k_phase3(
    const float* __restrict__ xs, const float* __restrict__ WB,
    const float* __restrict__ bB, const float* __restrict__ WC,
    const float* __restrict__ bC,
    const float* __restrict__ lnA, const float* __restrict__ dparam,
    const float* __restrict__ z, const float* __restrict__ carry,
    float* __restrict__ ys, float* __restrict__ hs){
  int t  = blockIdx.x*256 + threadIdx.x;
  int g  = t >> 12;
  int r  = t & 4095;
  int d  = r >> 2;
  int n4 = r & 3;
  float4 la = *(const float4*)(lnA + d*Nr + n4*4);
  float4 wb = *(const float4*)(WB  + n4*4);
  float4 bb = *(const float4*)(bB  + n4*4);
  float4 wcv= *(const float4*)(WC  + n4*4);
  float4 bcv= *(const float4*)(bC  + n4*4);
  float4 h0 = *(const float4*)(carry + (size_t)g*DN + d*Nr + n4*4);
  float lav[4] = {la.x,la.y,la.z,la.w};
  float wbv[4] = {wb.x,wb.y,wb.z,wb.w};
  float bbv[4] = {bb.x,bb.y,bb.z,bb.w};
  float wc[4]  = {wcv.x,wcv.y,wcv.z,wcv.w};
  float bc[4]  = {bcv.x,bcv.y,bcv.z,bcv.w};
  float h[4]   = {h0.x,h0.y,h0.z,h0.w};
  float ad2[4], p[4], q[4];
  #pragma unroll
  for (int j=0;j<4;j++){
    float a = -exp_hw(lav[j]);
    ad2[j] = a*LOG2E;
    float ia = 1.f/a;
    p[j]=wbv[j]*ia; q[j]=bbv[j]*ia;
  }
  float dp = dparam[d];
  int l0 = g*LC;
  #pragma unroll 2
  for (int i=0;i<LC;i++){
    int l = l0+i;
    float x  = xs[(size_t)l*Dr + d];
    float dl = softplus_fast(dp + z[l]);
    float x2 = x*x;
    float y = 0.f;
    #pragma unroll
    for (int j=0;j<4;j++){
      float Ab = exp2_hw(dl*ad2[j]);
      float Bx = (Ab-1.f)*fmaf(x2, p[j], x*q[j]);
      h[j] = fmaf(Ab, h[j], Bx);
      y = fmaf(h[j], fmaf(x, wc[j], bc[j]), y);
    }
    *(f32x4*)(hs + (size_t)l*DN + d*Nr + n4*4) = (f32x4){h[0],h[1],h[2],h[3]};
    // reduce y over the 4 n-lanes sharing this d (lanes 4k..4k+3)
    y += __shfl_xor(y, 1, 64);
    y += __shfl_xor(y, 2, 64);
    if (n4 == 0) ys[(size_t)l*Dr + d] = y;
  }
}

extern "C" void kernel_launch(void* const* d_in, const int* in_sizes, int n_in,
                              void* d_out, int out_size, void* d_ws, size_t ws_size,
                              hipStream_t stream) {
  const float* xs     = (const float*)d_in[0];
  const float* WB     = (const float*)d_in[1];
  const float* bB     = (const float*)d_in[2];
  const float* WC     = (const float*)d_in[3];
  const float* bC     = (const float*)d_in[4];
  const float* WD     = (const float*)d_in[5];
  const float* bD     = (const float*)d_in[6];
  const float* lnA    = (const float*)d_in[7];
  const float* dparam = (const float*)d_in[8];

  float* ys = (float*)d_out;
  float* hs = ys + (size_t)Lr*Dr;

  float* z     = (float*)d_ws;          // Lr
  float* aggA  = z + Lr;                // GDN (4 MB)
  float* aggB  = aggA + GDN;            // GDN
  float* carry = aggB + GDN;            // GDN  (total ~12.6 MB)

  k_rowdot<<<Lr, 256, 0, stream>>>(xs, WD, bD, z);
  k_phase1<<<(Gc*Dr*4)/256, 256, 0, stream>>>(xs, WB, bB, lnA, dparam, z, aggA, aggB);
  k_carry<<<DN/64, 64, 0, stream>>>(aggA, aggB, carry);
  k_phase3<<<(Gc*Dr*4)/256, 256, 0, stream>>>(xs, WB, bB, WC, bC, lnA, dparam, z, carry, ys, hs);
}